// Round 5
// baseline (1819.554 us; speedup 1.0000x reference)
//
#include <hip/hip_runtime.h>
#include <hip/hip_fp16.h>

typedef _Float16 half8 __attribute__((ext_vector_type(8)));
typedef float floatx4 __attribute__((ext_vector_type(4)));
typedef unsigned int u32x4 __attribute__((ext_vector_type(4)));

// B=128, T=512, E=256, H=512, OUT=9, L=2. Quirk: both layers use Uk_w[0]/Uk_b[0].
//
// zfrag layout (verified): 16B granules [t][bt][c16][b15]; granule g = c16*16+b15
// holds z[b = bt*16 + b15][h = c16*8 .. +8). Consumer lane (m,q) A-frag for
// K-block kk is granule (kk*4+q)*16 + m.
//
// ENCODED STORAGE: z stored as enc = z + 2 (f16 in [1,3], bits 0x3C00..0x4200).
// Poison 0xAA and zeros fall outside -> an 8B word is valid iff its low f16 is
// in range. Each z address transitions poison->final exactly ONCE, so any
// stale read returns poison (invalid), never valid-but-wrong.
//
// R5 change: L2 FAST-PATH HANDOFF. Sibling blocks of a bt are same-XCD by
// construction (blockIdx differs by 8). Producers add a plain 16B store
// (lands in the XCD L2) before the agstores (MALL, fallback path). Consumers
// poll with global_load_dwordx4 sc0 (L1-bypass, L2-served, 16B) for up to 3
// passes, then fall back to the VERIFIED agload loop. Correctness never
// depends on sc0 semantics or XCD placement (poison invariant + ag fallback).

union H8 { half8 v; unsigned long long u[2]; };

__device__ __forceinline__ unsigned long long agload(const unsigned long long* p) {
  return __hip_atomic_load(p, __ATOMIC_RELAXED, __HIP_MEMORY_SCOPE_AGENT);
}
__device__ __forceinline__ void agstore(unsigned long long* p, unsigned long long v) {
  __hip_atomic_store(p, v, __ATOMIC_RELAXED, __HIP_MEMORY_SCOPE_AGENT);
}
__device__ __forceinline__ bool valid16(unsigned long long u) {
  return (unsigned)((unsigned)(u & 0xFFFFull) - 0x3C00u) <= 0x600u;  // f16 in [1.0, 3.0]
}

// issue 4x16B L2-scope polls (thread tid covers granules tid + j*256)
__device__ __forceinline__ void l2_issue4(const unsigned long long* src, int tid, u32x4 r[4]) {
#pragma unroll
  for (int j = 0; j < 4; ++j) {
    const char* p = (const char*)(src + 2 * (tid + j * 256));
    asm volatile("global_load_dwordx4 %0, %1, off sc0" : "=&v"(r[j]) : "v"(p) : "memory");
  }
}

// fast L2 passes + verified agload fallback. g[8] = thread's 8 ull words.
__device__ __forceinline__ void poll_tile(const unsigned long long* src, int tid,
                                          unsigned long long g[8], unsigned need,
                                          int fastpasses, int sleep) {
  for (int p = 0; p < fastpasses && need; ++p) {
    u32x4 r[4];
    l2_issue4(src, tid, r);
    asm volatile("s_waitcnt vmcnt(0)" ::: "memory");
    __builtin_amdgcn_sched_barrier(0);
    unsigned nn = 0;
#pragma unroll
    for (int j = 0; j < 4; ++j) {
      unsigned long long lo = ((unsigned long long)r[j][1] << 32) | r[j][0];
      unsigned long long hi = ((unsigned long long)r[j][3] << 32) | r[j][2];
      if (need & (1u << (2 * j))) {
        if (valid16(lo)) g[2 * j] = lo; else nn |= (1u << (2 * j));
      }
      if (need & (1u << (2 * j + 1))) {
        if (valid16(hi)) g[2 * j + 1] = hi; else nn |= (1u << (2 * j + 1));
      }
    }
    need = nn;
  }
  while (need) {  // verified agload fallback, two-phase (1 RT per pass)
    if (sleep) __builtin_amdgcn_s_sleep(1);
    unsigned long long t[8];
#pragma unroll
    for (int i = 0; i < 8; ++i)
      if (need & (1u << i)) t[i] = agload(src + 2 * (tid + (i >> 1) * 256) + (i & 1));
    unsigned nn = 0;
#pragma unroll
    for (int i = 0; i < 8; ++i)
      if (need & (1u << i)) {
        if (valid16(t[i])) g[i] = t[i]; else nn |= (1u << i);
      }
    need = nn;
  }
}

// ---------------- prep: V pad, fused biases, f16-rounded weight row-sums ----------------
__global__ void prep_small(const float* __restrict__ Vw, const float* __restrict__ Vb,
                           const float* __restrict__ Wb, const float* __restrict__ Ukb,
                           const float* __restrict__ Wkb, const float* __restrict__ Ukw,
                           const float* __restrict__ Wkw, _Float16* __restrict__ V16,
                           float* __restrict__ bxp, float* __restrict__ bc,
                           float* __restrict__ sums) {
  int i = blockIdx.x * blockDim.x + threadIdx.x;
  if (i < 16 * 512) {
    int o = i >> 9, k = i & 511;
    V16[i] = (_Float16)(o < 9 ? Vw[o * 512 + k] : 0.0f);
  }
  if (i < 512) {
    bxp[i] = Wb[i] + Ukb[i];   // layer-0 pre-activation bias (folded into xp)
    bc[i]  = Wkb[i] + Ukb[i];  // layer-1 pre-activation bias
  }
  if (i < 1024) {  // sums[0..511]=rowsum f16(U); [512..1023]=rowsum f16(Wk)
    const float* row = (i < 512) ? Ukw + (size_t)i * 512 : Wkw + (size_t)(i - 512) * 512;
    float s = 0.f;
    for (int k = 0; k < 512; k += 4) {
      float4 v = *(const float4*)(row + k);
      s += (float)(_Float16)v.x + (float)(_Float16)v.y + (float)(_Float16)v.z + (float)(_Float16)v.w;
    }
    sums[i] = s;
  } else if (i < 1040) {  // sums[1024..1039] = out bias: Vb - 2*rowsum f16(V)
    int o = i - 1024;
    float s = 0.f;
    if (o < 9) {
      const float* row = Vw + (size_t)o * 512;
      for (int k = 0; k < 512; k += 4) {
        float4 v = *(const float4*)(row + k);
        s += (float)(_Float16)v.x + (float)(_Float16)v.y + (float)(_Float16)v.z + (float)(_Float16)v.w;
      }
    }
    sums[i] = (o < 9 ? Vb[o] : 0.f) - 2.f * s;
  }
}

// ---------------- xp GEMM: xp[t][b][:] = emb[b][t][:] @ W^T + (Wb+Ukb0), f32 in, f16 out ----
__global__ __launch_bounds__(256) void gemm_xp(const float* __restrict__ Aptr,
                                               const float* __restrict__ Bptr,
                                               _Float16* __restrict__ Cout,
                                               const float* __restrict__ bias) {
  const int K = 256;
  __shared__ __align__(16) _Float16 As[128][40];
  __shared__ __align__(16) _Float16 Bs[128][40];
  const int tid = threadIdx.x;
  const int bm = blockIdx.x, bn = blockIdx.y;
  const int w = tid >> 6, lane = tid & 63;
  const int m = lane & 15, q = lane >> 4;

  floatx4 acc[2][8];
#pragma unroll
  for (int i = 0; i < 2; ++i)
#pragma unroll
    for (int j = 0; j < 8; ++j) acc[i][j] = (floatx4){0.f, 0.f, 0.f, 0.f};

  for (int kt = 0; kt < (K >> 5); ++kt) {
    const int k0 = kt << 5;
    __syncthreads();
#pragma unroll
    for (int it = 0; it < 2; ++it) {
      int idx = tid + it * 256;
      int row = idx >> 2, ch = idx & 3;
      size_t gA = (size_t)(bm * 128 + row) * K + (k0 + ch * 8);
      const float4* p = (const float4*)(Aptr + gA);
      float4 f0 = p[0], f1 = p[1];
      *(half8*)&As[row][ch * 8] =
          (half8){(_Float16)f0.x, (_Float16)f0.y, (_Float16)f0.z, (_Float16)f0.w,
                  (_Float16)f1.x, (_Float16)f1.y, (_Float16)f1.z, (_Float16)f1.w};
      size_t gB = (size_t)(bn * 128 + row) * K + (k0 + ch * 8);
      const float4* pb = (const float4*)(Bptr + gB);
      float4 g0 = pb[0], g1 = pb[1];
      *(half8*)&Bs[row][ch * 8] =
          (half8){(_Float16)g0.x, (_Float16)g0.y, (_Float16)g0.z, (_Float16)g0.w,
                  (_Float16)g1.x, (_Float16)g1.y, (_Float16)g1.z, (_Float16)g1.w};
    }
    __syncthreads();
    half8 a[2], b[8];
#pragma unroll
    for (int i = 0; i < 2; ++i) a[i] = *(const half8*)&As[w * 32 + i * 16 + m][q * 8];
#pragma unroll
    for (int j = 0; j < 8; ++j) b[j] = *(const half8*)&Bs[j * 16 + m][q * 8];
#pragma unroll
    for (int i = 0; i < 2; ++i)
#pragma unroll
      for (int j = 0; j < 8; ++j)
        acc[i][j] = __builtin_amdgcn_mfma_f32_16x16x32_f16(a[i], b[j], acc[i][j], 0, 0, 0);
  }
#pragma unroll
  for (int i = 0; i < 2; ++i)
#pragma unroll
    for (int j = 0; j < 8; ++j) {
      int col = bn * 128 + j * 16 + m;
      float bv = bias[col];
#pragma unroll
      for (int rr = 0; rr < 4; ++rr) {
        int row = bm * 128 + w * 32 + i * 16 + q * 4 + rr;  // row = b*512 + t
        size_t orow = (size_t)(row & 511) * 128 + (row >> 9);  // -> t*128 + b
        Cout[orow * 512 + col] = (_Float16)(acc[i][j][rr] + bv);
      }
    }
}

// ---------------- poll+load one 16KB z tile into LDS (validity = data range) --------------
template <int SLEEP>
__device__ __forceinline__ void stage_tile(const _Float16* srcTile, _Float16* dst, int tid) {
  const unsigned long long* src = (const unsigned long long*)srcTile;
  unsigned long long g[8];
  poll_tile(src, tid, g, 0xFFu, 3, SLEEP);
#pragma unroll
  for (int j = 0; j < 4; ++j) {
    H8 t;
    t.u[0] = g[2 * j];
    t.u[1] = g[2 * j + 1];
    *(half8*)&dst[(tid + j * 256) * 8] = t.v;
  }
}

// ---------------- fused 2-layer recurrence, data-polling, encoded z ----------------
// 64 blocks x 256 thr. layer = blk>>5, bt = blk&7, ct = (blk>>3)&3.
// Block: batch rows [bt*16,+16), cols [ct*128,+128). U (and Wk for L1) register-resident.
__global__ __launch_bounds__(256, 1) void rnn_fused2(const float* __restrict__ Uw,
                                                     const float* __restrict__ Wkw,
                                                     const _Float16* __restrict__ xp,
                                                     _Float16* __restrict__ z0f,
                                                     _Float16* __restrict__ z1f,
                                                     const float* __restrict__ bc,
                                                     const float* __restrict__ sums) {
  __shared__ __align__(16) _Float16 az[2][8192];  // own-layer z_prev tiles (32 KB, L0 dbuf)
  __shared__ __align__(16) _Float16 azs[8192];    // L1: z0(s) shadow tile (16 KB)
  __shared__ __align__(16) _Float16 zo[4][16][40];  // per-wave output transpose (5 KB)
  const int tid = threadIdx.x;
  const int layer = blockIdx.x >> 5, bt = blockIdx.x & 7, ct = (blockIdx.x >> 3) & 3;
  const int lane = tid & 63, w = tid >> 6, m = lane & 15, q = lane >> 4;
  const int colbase = ct * 128 + w * 32;
  const int cs = ct * 4 + w;  // wave's own c16-quad base (granule block it stores)

  half8 ufr[2][16], wfr[2][16];
#pragma unroll
  for (int t = 0; t < 2; ++t) {
    const float* up = Uw + (size_t)(colbase + t * 16 + m) * 512 + q * 8;
    const float* wp = Wkw + (size_t)(colbase + t * 16 + m) * 512 + q * 8;
#pragma unroll
    for (int kk = 0; kk < 16; ++kk) {
      float4 f0 = *(const float4*)(up + kk * 32), f1 = *(const float4*)(up + kk * 32 + 4);
      ufr[t][kk] = (half8){(_Float16)f0.x, (_Float16)f0.y, (_Float16)f0.z, (_Float16)f0.w,
                           (_Float16)f1.x, (_Float16)f1.y, (_Float16)f1.z, (_Float16)f1.w};
      if (layer) {
        float4 g0 = *(const float4*)(wp + kk * 32), g1 = *(const float4*)(wp + kk * 32 + 4);
        wfr[t][kk] = (half8){(_Float16)g0.x, (_Float16)g0.y, (_Float16)g0.z, (_Float16)g0.w,
                             (_Float16)g1.x, (_Float16)g1.y, (_Float16)g1.z, (_Float16)g1.w};
      }
    }
  }
  const float corrU[2] = {-2.f * sums[colbase + m], -2.f * sums[colbase + 16 + m]};
  float cw[2] = {0.f, 0.f};
  if (layer) {
    cw[0] = -2.f * sums[512 + colbase + m] + bc[colbase + m];
    cw[1] = -2.f * sums[512 + colbase + 16 + m] + bc[colbase + 16 + m];
  }

  _Float16* zout = layer ? z1f : z0f;

  if (layer) stage_tile<1>(z0f + (size_t)bt * 8192, azs, tid);  // z0(0)

  for (int s = 0; s < 512; ++s) {
    float pin[8];
    if (layer == 0) {  // input term: issue early, consumed after MFMAs
      const _Float16* xb = xp + (size_t)s * 65536 + (size_t)(bt * 16) * 512;
#pragma unroll
      for (int t = 0; t < 2; ++t)
#pragma unroll
        for (int rr = 0; rr < 4; ++rr)
          pin[t * 4 + rr] = (float)xb[(size_t)(q * 4 + rr) * 512 + colbase + t * 16 + m];
    }

    floatx4 wk[2];
    wk[0] = (floatx4){0.f, 0.f, 0.f, 0.f};
    wk[1] = (floatx4){0.f, 0.f, 0.f, 0.f};
    _Float16* azcur = layer ? az[0] : az[s & 1];
    if (layer) {
      __syncthreads();  // (A) publish azs (prev tail); az WAR
      const unsigned long long* src =
          (const unsigned long long*)(z1f + ((size_t)(s - 1) * 8 + bt) * 8192);
      u32x4 rr4[4];
      if (s > 0) l2_issue4(src, tid, rr4);  // z1(s-1) first-pass, in flight during Wk MFMAs
#pragma unroll
      for (int kk = 0; kk < 16; ++kk) {  // Wk @ z0(s) (encoded; corrected via cw)
        half8 a = *(const half8*)&azs[((kk * 4 + q) * 16 + m) * 8];
        wk[0] = __builtin_amdgcn_mfma_f32_16x16x32_f16(a, wfr[0][kk], wk[0], 0, 0, 0);
        wk[1] = __builtin_amdgcn_mfma_f32_16x16x32_f16(a, wfr[1][kk], wk[1], 0, 0, 0);
      }
      if (s > 0) {
        asm volatile("s_waitcnt vmcnt(0)" ::: "memory");
        __builtin_amdgcn_sched_barrier(0);
        unsigned long long g[8];
        unsigned need = 0;
#pragma unroll
        for (int j = 0; j < 4; ++j) {
          unsigned long long lo = ((unsigned long long)rr4[j][1] << 32) | rr4[j][0];
          unsigned long long hi = ((unsigned long long)rr4[j][3] << 32) | rr4[j][2];
          if (valid16(lo)) g[2 * j] = lo; else need |= (1u << (2 * j));
          if (valid16(hi)) g[2 * j + 1] = hi; else need |= (1u << (2 * j + 1));
        }
        poll_tile(src, tid, g, need, 2, 0);
#pragma unroll
        for (int j = 0; j < 4; ++j) {
          H8 t;
          t.u[0] = g[2 * j];
          t.u[1] = g[2 * j + 1];
          *(half8*)&azcur[(tid + j * 256) * 8] = t.v;
        }
      }
    } else {
      if (s > 0) stage_tile<0>(z0f + ((size_t)(s - 1) * 8 + bt) * 8192, azcur, tid);
    }
    __syncthreads();  // (A2) publish az

    floatx4 acc[2][2];
    acc[0][0] = (floatx4){0.f, 0.f, 0.f, 0.f};
    acc[0][1] = (floatx4){0.f, 0.f, 0.f, 0.f};
    acc[1][0] = (floatx4){0.f, 0.f, 0.f, 0.f};
    acc[1][1] = (floatx4){0.f, 0.f, 0.f, 0.f};
    if (s > 0) {
#pragma unroll
      for (int kk = 0; kk < 16; ++kk) {  // U @ z_prev (encoded; corrected via corrU)
        half8 a = *(const half8*)&azcur[((kk * 4 + q) * 16 + m) * 8];
        acc[0][kk & 1] = __builtin_amdgcn_mfma_f32_16x16x32_f16(a, ufr[0][kk], acc[0][kk & 1], 0, 0, 0);
        acc[1][kk & 1] = __builtin_amdgcn_mfma_f32_16x16x32_f16(a, ufr[1][kk], acc[1][kk & 1], 0, 0, 0);
      }
    }
#pragma unroll
    for (int t = 0; t < 2; ++t)
#pragma unroll
      for (int rr = 0; rr < 4; ++rr) {
        float x = layer ? (wk[t][rr] + cw[t]) : pin[t * 4 + rr];
        if (s > 0) x += acc[t][0][rr] + acc[t][1][rr] + corrU[t];
        // enc = tanh(x) + 2 = 3 - 2/(exp2(x*2/ln2)+1)
        float e = __builtin_exp2f(x * 2.885390081777927f);
        float enc = 3.f - 2.f * __builtin_amdgcn_rcpf(e + 1.f);
        zo[w][q * 4 + rr][t * 16 + m] = (_Float16)enc;
      }
    asm volatile("s_waitcnt lgkmcnt(0)" ::: "memory");  // wave-sync LDS w->r
    __builtin_amdgcn_sched_barrier(0);
    {
      H8 pv;
      pv.v = *(const half8*)&zo[w][m][q * 8];  // granule (cs*4+q, m)
      unsigned long long* dst =
          (unsigned long long*)((char*)zout +
                                (((size_t)s * 8 + bt) * 1024 + (size_t)(cs * 4 + q) * 16 + m) * 16);
      u32x4 pd;
      pd[0] = (unsigned)pv.u[0];
      pd[1] = (unsigned)(pv.u[0] >> 32);
      pd[2] = (unsigned)pv.u[1];
      pd[3] = (unsigned)(pv.u[1] >> 32);
      // plain 16B store -> lands in local XCD L2 (fast path for same-XCD readers)
      asm volatile("global_store_dwordx4 %0, %1, off" :: "v"(dst), "v"(pd) : "memory");
      // agent-scope publish (MALL) -> correctness fallback path
      agstore(dst, pv.u[0]);
      agstore(dst + 1, pv.u[1]);
    }
    if (layer && s < 511)  // shadow: stage z0(s+1) for next step's Wk part
      stage_tile<1>(z0f + ((size_t)(s + 1) * 8 + bt) * 8192, azs, tid);
  }
}

// ---------------- y = z1 @ V^T + bco : z1 encoded in zfrag layout ----------------
__global__ __launch_bounds__(64) void out_gemm(const _Float16* __restrict__ z1,
                                               const _Float16* __restrict__ V16,
                                               const float* __restrict__ bco,
                                               float* __restrict__ out) {
  __shared__ __align__(16) _Float16 zt[16][520];
  __shared__ __align__(16) _Float16 vt[16][520];
  const int tid = threadIdx.x;
  const int m = tid & 15, q = tid >> 4;
  const size_t r0 = (size_t)blockIdx.x * 16;  // r = t*128 + b
  for (int idx = tid; idx < 1024; idx += 64) {
    int row = idx >> 6, ch = idx & 63;
    int r = (int)(r0 + row), t = r >> 7, b = r & 127;
    size_t off = (size_t)(t * 8 + (b >> 4)) * 8192 + (size_t)ch * 128 + (b & 15) * 8;
    *(half8*)&zt[row][ch * 8] = *(const half8*)&z1[off];
    *(half8*)&vt[row][ch * 8] = *(const half8*)&V16[(size_t)row * 512 + ch * 8];
  }
  __syncthreads();
  floatx4 acc = {0.f, 0.f, 0.f, 0.f};
#pragma unroll
  for (int kk = 0; kk < 16; ++kk) {
    half8 a = *(const half8*)&zt[m][kk * 32 + q * 8];
    half8 b = *(const half8*)&vt[m][kk * 32 + q * 8];
    acc = __builtin_amdgcn_mfma_f32_16x16x32_f16(a, b, acc, 0, 0, 0);
  }
  if (m < 9) {
#pragma unroll
    for (int rr = 0; rr < 4; ++rr) {
      size_t r = r0 + q * 4 + rr;
      size_t t = r >> 7, b = r & 127;
      out[(b * 512 + t) * 9 + m] = acc[rr] + bco[m];
    }
  }
}

extern "C" void kernel_launch(void* const* d_in, const int* in_sizes, int n_in,
                              void* d_out, int out_size, void* d_ws, size_t ws_size,
                              hipStream_t stream) {
  const float* emb = (const float*)d_in[0];  // [128][512][256]
  const float* Ww  = (const float*)d_in[1];  // [512][256]
  const float* Wb  = (const float*)d_in[2];  // [512]
  const float* Ukw = (const float*)d_in[3];  // [2][512][512] (only [0] used)
  const float* Ukb = (const float*)d_in[4];  // [2][512]      (only [0] used)
  const float* Wkw = (const float*)d_in[5];  // [1][512][512]
  const float* Wkb = (const float*)d_in[6];  // [1][512]
  const float* Vw  = (const float*)d_in[7];  // [9][512]
  const float* Vb  = (const float*)d_in[8];  // [9]
  float* out = (float*)d_out;                // [128][512][9] f32

  char* ws = (char*)d_ws;
  _Float16* xp   = (_Float16*)(ws + 0);          // [T][B][H] f16 t-major, 64 MB
  _Float16* z0f  = (_Float16*)(ws + 67108864);   // zfrag (encoded), 64 MB
  _Float16* z1f  = (_Float16*)(ws + 134217728);  // zfrag (encoded), 64 MB
  _Float16* V16  = (_Float16*)(ws + 201326592);  // 16 KB
  float* bxp     = (float*)(ws + 201342976);
  float* bc      = (float*)(ws + 201345024);
  float* sums    = (float*)(ws + 201347072);     // SU[512], SW[512], bco[16]

  hipLaunchKernelGGL(prep_small, dim3(32), dim3(256), 0, stream,
                     Vw, Vb, Wb, Ukb, Wkb, Ukw, Wkw, V16, bxp, bc, sums);
  hipLaunchKernelGGL(gemm_xp, dim3(512, 4), dim3(256), 0, stream, emb, Ww, xp, bxp);
  hipLaunchKernelGGL(rnn_fused2, dim3(64), dim3(256), 0, stream,
                     Ukw, Wkw, xp, z0f, z1f, bc, sums);
  hipLaunchKernelGGL(out_gemm, dim3(4096), dim3(64), 0, stream, z1f, V16, sums + 1024, out);
}

// Round 6
// 1623.049 us; speedup vs baseline: 1.1211x; 1.1211x over previous
//
#include <hip/hip_runtime.h>
#include <hip/hip_fp16.h>

typedef _Float16 half8 __attribute__((ext_vector_type(8)));
typedef float floatx4 __attribute__((ext_vector_type(4)));
typedef unsigned int u32x4 __attribute__((ext_vector_type(4)));

// B=128, T=512, E=256, H=512, OUT=9, L=2. Quirk: both layers use Uk_w[0]/Uk_b[0].
//
// zfrag layout (verified): 16B granules [t][bt][c16][b15]; granule g = c16*16+b15
// holds z[b = bt*16 + b15][h = c16*8 .. +8). Consumer lane (m,q) A-frag for
// K-block kk is granule (kk*4+q)*16 + m.
//
// ENCODED STORAGE: z stored as enc = z + 2 (f16 in [1,3], bits 0x3C00..0x4200).
// Poison 0xAA and zeros fall outside -> an 8B word is valid iff its low f16 is
// in range. Each z address transitions poison->final exactly ONCE, so any
// stale/torn read returns poison (invalid), never valid-but-wrong.
//
// R6 change: 16B COHERENT POLLS AND STORES. Theory (R3/R4/R5 evidence): the
// handoff is bound by MALL service THROUGHPUT on small agent ops, not RT
// latency. All polls -> global_load_dwordx4 sc0 sc1 (agent-coherent, bypasses
// L1+L2 like agload -> no stale-L2 hazard, no fallback needed); producer
// publish -> ONE global_store_dwordx4 sc0 sc1 (replaces 2x8B agstores; also
// removes R5's duplicate plain store + its dirty-L2 writebacks). One wave
// instruction now covers 1KB contiguous = 1 request per 64B line: half the
// baseline's request count on both sides. Validity stays per-8B half.

union H8 { half8 v; unsigned long long u[2]; };

__device__ __forceinline__ bool valid16(unsigned long long u) {
  return (unsigned)((unsigned)(u & 0xFFFFull) - 0x3C00u) <= 0x600u;  // f16 in [1.0, 3.0]
}

// retry loop: reload only needed 16B words (need = 8-bit mask over 8B halves)
__device__ __forceinline__ void poll16(const unsigned long long* src, int tid,
                                       unsigned long long g[8], unsigned need, int sleep) {
  while (need) {
    u32x4 r[4];
#pragma unroll
    for (int j = 0; j < 4; ++j)
      if (need & (3u << (2 * j))) {
        const char* p = (const char*)(src + 2 * (tid + j * 256));
        asm volatile("global_load_dwordx4 %0, %1, off sc0 sc1"
                     : "=&v"(r[j]) : "v"(p) : "memory");
      }
    asm volatile("s_waitcnt vmcnt(0)" ::: "memory");
    __builtin_amdgcn_sched_barrier(0);
    unsigned nn = 0;
#pragma unroll
    for (int j = 0; j < 4; ++j) {
      if (!(need & (3u << (2 * j)))) continue;
      unsigned long long lo = ((unsigned long long)r[j][1] << 32) | r[j][0];
      unsigned long long hi = ((unsigned long long)r[j][3] << 32) | r[j][2];
      if (need & (1u << (2 * j))) { if (valid16(lo)) g[2 * j] = lo; else nn |= (1u << (2 * j)); }
      if (need & (2u << (2 * j))) { if (valid16(hi)) g[2 * j + 1] = hi; else nn |= (2u << (2 * j)); }
    }
    need = nn;
    if (need && sleep) __builtin_amdgcn_s_sleep(1);
  }
}

// ---------------- prep: V pad, fused biases, f16-rounded weight row-sums ----------------
__global__ void prep_small(const float* __restrict__ Vw, const float* __restrict__ Vb,
                           const float* __restrict__ Wb, const float* __restrict__ Ukb,
                           const float* __restrict__ Wkb, const float* __restrict__ Ukw,
                           const float* __restrict__ Wkw, _Float16* __restrict__ V16,
                           float* __restrict__ bxp, float* __restrict__ bc,
                           float* __restrict__ sums) {
  int i = blockIdx.x * blockDim.x + threadIdx.x;
  if (i < 16 * 512) {
    int o = i >> 9, k = i & 511;
    V16[i] = (_Float16)(o < 9 ? Vw[o * 512 + k] : 0.0f);
  }
  if (i < 512) {
    bxp[i] = Wb[i] + Ukb[i];   // layer-0 pre-activation bias (folded into xp)
    bc[i]  = Wkb[i] + Ukb[i];  // layer-1 pre-activation bias
  }
  if (i < 1024) {  // sums[0..511]=rowsum f16(U); [512..1023]=rowsum f16(Wk)
    const float* row = (i < 512) ? Ukw + (size_t)i * 512 : Wkw + (size_t)(i - 512) * 512;
    float s = 0.f;
    for (int k = 0; k < 512; k += 4) {
      float4 v = *(const float4*)(row + k);
      s += (float)(_Float16)v.x + (float)(_Float16)v.y + (float)(_Float16)v.z + (float)(_Float16)v.w;
    }
    sums[i] = s;
  } else if (i < 1040) {  // sums[1024..1039] = out bias: Vb - 2*rowsum f16(V)
    int o = i - 1024;
    float s = 0.f;
    if (o < 9) {
      const float* row = Vw + (size_t)o * 512;
      for (int k = 0; k < 512; k += 4) {
        float4 v = *(const float4*)(row + k);
        s += (float)(_Float16)v.x + (float)(_Float16)v.y + (float)(_Float16)v.z + (float)(_Float16)v.w;
      }
    }
    sums[i] = (o < 9 ? Vb[o] : 0.f) - 2.f * s;
  }
}

// ---------------- xp GEMM: xp[t][b][:] = emb[b][t][:] @ W^T + (Wb+Ukb0), f32 in, f16 out ----
__global__ __launch_bounds__(256) void gemm_xp(const float* __restrict__ Aptr,
                                               const float* __restrict__ Bptr,
                                               _Float16* __restrict__ Cout,
                                               const float* __restrict__ bias) {
  const int K = 256;
  __shared__ __align__(16) _Float16 As[128][40];
  __shared__ __align__(16) _Float16 Bs[128][40];
  const int tid = threadIdx.x;
  const int bm = blockIdx.x, bn = blockIdx.y;
  const int w = tid >> 6, lane = tid & 63;
  const int m = lane & 15, q = lane >> 4;

  floatx4 acc[2][8];
#pragma unroll
  for (int i = 0; i < 2; ++i)
#pragma unroll
    for (int j = 0; j < 8; ++j) acc[i][j] = (floatx4){0.f, 0.f, 0.f, 0.f};

  for (int kt = 0; kt < (K >> 5); ++kt) {
    const int k0 = kt << 5;
    __syncthreads();
#pragma unroll
    for (int it = 0; it < 2; ++it) {
      int idx = tid + it * 256;
      int row = idx >> 2, ch = idx & 3;
      size_t gA = (size_t)(bm * 128 + row) * K + (k0 + ch * 8);
      const float4* p = (const float4*)(Aptr + gA);
      float4 f0 = p[0], f1 = p[1];
      *(half8*)&As[row][ch * 8] =
          (half8){(_Float16)f0.x, (_Float16)f0.y, (_Float16)f0.z, (_Float16)f0.w,
                  (_Float16)f1.x, (_Float16)f1.y, (_Float16)f1.z, (_Float16)f1.w};
      size_t gB = (size_t)(bn * 128 + row) * K + (k0 + ch * 8);
      const float4* pb = (const float4*)(Bptr + gB);
      float4 g0 = pb[0], g1 = pb[1];
      *(half8*)&Bs[row][ch * 8] =
          (half8){(_Float16)g0.x, (_Float16)g0.y, (_Float16)g0.z, (_Float16)g0.w,
                  (_Float16)g1.x, (_Float16)g1.y, (_Float16)g1.z, (_Float16)g1.w};
    }
    __syncthreads();
    half8 a[2], b[8];
#pragma unroll
    for (int i = 0; i < 2; ++i) a[i] = *(const half8*)&As[w * 32 + i * 16 + m][q * 8];
#pragma unroll
    for (int j = 0; j < 8; ++j) b[j] = *(const half8*)&Bs[j * 16 + m][q * 8];
#pragma unroll
    for (int i = 0; i < 2; ++i)
#pragma unroll
      for (int j = 0; j < 8; ++j)
        acc[i][j] = __builtin_amdgcn_mfma_f32_16x16x32_f16(a[i], b[j], acc[i][j], 0, 0, 0);
  }
#pragma unroll
  for (int i = 0; i < 2; ++i)
#pragma unroll
    for (int j = 0; j < 8; ++j) {
      int col = bn * 128 + j * 16 + m;
      float bv = bias[col];
#pragma unroll
      for (int rr = 0; rr < 4; ++rr) {
        int row = bm * 128 + w * 32 + i * 16 + q * 4 + rr;  // row = b*512 + t
        size_t orow = (size_t)(row & 511) * 128 + (row >> 9);  // -> t*128 + b
        Cout[orow * 512 + col] = (_Float16)(acc[i][j][rr] + bv);
      }
    }
}

// ---------------- poll+load one 16KB z tile into LDS (validity = data range) --------------
template <int SLEEP>
__device__ __forceinline__ void stage_tile(const _Float16* srcTile, _Float16* dst, int tid) {
  const unsigned long long* src = (const unsigned long long*)srcTile;
  u32x4 r[4];
#pragma unroll
  for (int j = 0; j < 4; ++j) {  // first pass: 4x16B coherent loads, pipelined
    const char* p = (const char*)(src + 2 * (tid + j * 256));
    asm volatile("global_load_dwordx4 %0, %1, off sc0 sc1" : "=&v"(r[j]) : "v"(p) : "memory");
  }
  asm volatile("s_waitcnt vmcnt(0)" ::: "memory");
  __builtin_amdgcn_sched_barrier(0);
  unsigned long long g[8];
  unsigned need = 0;
#pragma unroll
  for (int j = 0; j < 4; ++j) {
    unsigned long long lo = ((unsigned long long)r[j][1] << 32) | r[j][0];
    unsigned long long hi = ((unsigned long long)r[j][3] << 32) | r[j][2];
    if (valid16(lo)) g[2 * j] = lo; else need |= (1u << (2 * j));
    if (valid16(hi)) g[2 * j + 1] = hi; else need |= (2u << (2 * j));
  }
  poll16(src, tid, g, need, SLEEP);
#pragma unroll
  for (int j = 0; j < 4; ++j) {
    H8 t;
    t.u[0] = g[2 * j];
    t.u[1] = g[2 * j + 1];
    *(half8*)&dst[(tid + j * 256) * 8] = t.v;
  }
}

// ---------------- fused 2-layer recurrence, data-polling, encoded z ----------------
// 64 blocks x 256 thr. layer = blk>>5, bt = blk&7, ct = (blk>>3)&3.
// Block: batch rows [bt*16,+16), cols [ct*128,+128). U (and Wk for L1) register-resident.
__global__ __launch_bounds__(256, 1) void rnn_fused2(const float* __restrict__ Uw,
                                                     const float* __restrict__ Wkw,
                                                     const _Float16* __restrict__ xp,
                                                     _Float16* __restrict__ z0f,
                                                     _Float16* __restrict__ z1f,
                                                     const float* __restrict__ bc,
                                                     const float* __restrict__ sums) {
  __shared__ __align__(16) _Float16 az[2][8192];  // own-layer z_prev tiles (32 KB, L0 dbuf)
  __shared__ __align__(16) _Float16 azs[8192];    // L1: z0(s) shadow tile (16 KB)
  __shared__ __align__(16) _Float16 zo[4][16][40];  // per-wave output transpose (5 KB)
  const int tid = threadIdx.x;
  const int layer = blockIdx.x >> 5, bt = blockIdx.x & 7, ct = (blockIdx.x >> 3) & 3;
  const int lane = tid & 63, w = tid >> 6, m = lane & 15, q = lane >> 4;
  const int colbase = ct * 128 + w * 32;
  const int cs = ct * 4 + w;  // wave's own c16-quad base (granule block it stores)

  half8 ufr[2][16], wfr[2][16];
#pragma unroll
  for (int t = 0; t < 2; ++t) {
    const float* up = Uw + (size_t)(colbase + t * 16 + m) * 512 + q * 8;
    const float* wp = Wkw + (size_t)(colbase + t * 16 + m) * 512 + q * 8;
#pragma unroll
    for (int kk = 0; kk < 16; ++kk) {
      float4 f0 = *(const float4*)(up + kk * 32), f1 = *(const float4*)(up + kk * 32 + 4);
      ufr[t][kk] = (half8){(_Float16)f0.x, (_Float16)f0.y, (_Float16)f0.z, (_Float16)f0.w,
                           (_Float16)f1.x, (_Float16)f1.y, (_Float16)f1.z, (_Float16)f1.w};
      if (layer) {
        float4 g0 = *(const float4*)(wp + kk * 32), g1 = *(const float4*)(wp + kk * 32 + 4);
        wfr[t][kk] = (half8){(_Float16)g0.x, (_Float16)g0.y, (_Float16)g0.z, (_Float16)g0.w,
                             (_Float16)g1.x, (_Float16)g1.y, (_Float16)g1.z, (_Float16)g1.w};
      }
    }
  }
  const float corrU[2] = {-2.f * sums[colbase + m], -2.f * sums[colbase + 16 + m]};
  float cw[2] = {0.f, 0.f};
  if (layer) {
    cw[0] = -2.f * sums[512 + colbase + m] + bc[colbase + m];
    cw[1] = -2.f * sums[512 + colbase + 16 + m] + bc[colbase + 16 + m];
  }

  _Float16* zout = layer ? z1f : z0f;

  if (layer) stage_tile<1>(z0f + (size_t)bt * 8192, azs, tid);  // z0(0)

  for (int s = 0; s < 512; ++s) {
    float pin[8];
    if (layer == 0) {  // input term: issue early, consumed after MFMAs
      const _Float16* xb = xp + (size_t)s * 65536 + (size_t)(bt * 16) * 512;
#pragma unroll
      for (int t = 0; t < 2; ++t)
#pragma unroll
        for (int rr = 0; rr < 4; ++rr)
          pin[t * 4 + rr] = (float)xb[(size_t)(q * 4 + rr) * 512 + colbase + t * 16 + m];
    }

    floatx4 wk[2];
    wk[0] = (floatx4){0.f, 0.f, 0.f, 0.f};
    wk[1] = (floatx4){0.f, 0.f, 0.f, 0.f};
    _Float16* azcur = layer ? az[0] : az[s & 1];
    if (layer) {
      __syncthreads();  // (A) publish azs (prev tail); az WAR
      const unsigned long long* src =
          (const unsigned long long*)(z1f + ((size_t)(s - 1) * 8 + bt) * 8192);
      u32x4 r16[4];
      if (s > 0) {  // z1(s-1) first-pass 16B loads, in flight during Wk MFMAs
#pragma unroll
        for (int j = 0; j < 4; ++j) {
          const char* p = (const char*)(src + 2 * (tid + j * 256));
          asm volatile("global_load_dwordx4 %0, %1, off sc0 sc1"
                       : "=&v"(r16[j]) : "v"(p) : "memory");
        }
      }
#pragma unroll
      for (int kk = 0; kk < 16; ++kk) {  // Wk @ z0(s) (encoded; corrected via cw)
        half8 a = *(const half8*)&azs[((kk * 4 + q) * 16 + m) * 8];
        wk[0] = __builtin_amdgcn_mfma_f32_16x16x32_f16(a, wfr[0][kk], wk[0], 0, 0, 0);
        wk[1] = __builtin_amdgcn_mfma_f32_16x16x32_f16(a, wfr[1][kk], wk[1], 0, 0, 0);
      }
      if (s > 0) {
        asm volatile("s_waitcnt vmcnt(0)" ::: "memory");
        __builtin_amdgcn_sched_barrier(0);
        unsigned long long g[8];
        unsigned need = 0;
#pragma unroll
        for (int j = 0; j < 4; ++j) {
          unsigned long long lo = ((unsigned long long)r16[j][1] << 32) | r16[j][0];
          unsigned long long hi = ((unsigned long long)r16[j][3] << 32) | r16[j][2];
          if (valid16(lo)) g[2 * j] = lo; else need |= (1u << (2 * j));
          if (valid16(hi)) g[2 * j + 1] = hi; else need |= (2u << (2 * j));
        }
        poll16(src, tid, g, need, 0);
#pragma unroll
        for (int j = 0; j < 4; ++j) {
          H8 t;
          t.u[0] = g[2 * j];
          t.u[1] = g[2 * j + 1];
          *(half8*)&azcur[(tid + j * 256) * 8] = t.v;
        }
      }
    } else {
      if (s > 0) stage_tile<0>(z0f + ((size_t)(s - 1) * 8 + bt) * 8192, azcur, tid);
    }
    __syncthreads();  // (A2) publish az

    floatx4 acc[2][2];
    acc[0][0] = (floatx4){0.f, 0.f, 0.f, 0.f};
    acc[0][1] = (floatx4){0.f, 0.f, 0.f, 0.f};
    acc[1][0] = (floatx4){0.f, 0.f, 0.f, 0.f};
    acc[1][1] = (floatx4){0.f, 0.f, 0.f, 0.f};
    if (s > 0) {
#pragma unroll
      for (int kk = 0; kk < 16; ++kk) {  // U @ z_prev (encoded; corrected via corrU)
        half8 a = *(const half8*)&azcur[((kk * 4 + q) * 16 + m) * 8];
        acc[0][kk & 1] = __builtin_amdgcn_mfma_f32_16x16x32_f16(a, ufr[0][kk], acc[0][kk & 1], 0, 0, 0);
        acc[1][kk & 1] = __builtin_amdgcn_mfma_f32_16x16x32_f16(a, ufr[1][kk], acc[1][kk & 1], 0, 0, 0);
      }
    }
#pragma unroll
    for (int t = 0; t < 2; ++t)
#pragma unroll
      for (int rr = 0; rr < 4; ++rr) {
        float x = layer ? (wk[t][rr] + cw[t]) : pin[t * 4 + rr];
        if (s > 0) x += acc[t][0][rr] + acc[t][1][rr] + corrU[t];
        // enc = tanh(x) + 2 = 3 - 2/(exp2(x*2/ln2)+1)
        float e = __builtin_exp2f(x * 2.885390081777927f);
        float enc = 3.f - 2.f * __builtin_amdgcn_rcpf(e + 1.f);
        zo[w][q * 4 + rr][t * 16 + m] = (_Float16)enc;
      }
    asm volatile("s_waitcnt lgkmcnt(0)" ::: "memory");  // wave-sync LDS w->r
    __builtin_amdgcn_sched_barrier(0);
    {
      H8 pv;
      pv.v = *(const half8*)&zo[w][m][q * 8];  // granule (cs*4+q, m)
      unsigned long long* dst =
          (unsigned long long*)((char*)zout +
                                (((size_t)s * 8 + bt) * 1024 + (size_t)(cs * 4 + q) * 16 + m) * 16);
      u32x4 pd;
      pd[0] = (unsigned)pv.u[0];
      pd[1] = (unsigned)(pv.u[0] >> 32);
      pd[2] = (unsigned)pv.u[1];
      pd[3] = (unsigned)(pv.u[1] >> 32);
      // single 16B coherent publish (agent-visible at the coherence point)
      asm volatile("global_store_dwordx4 %0, %1, off sc0 sc1" :: "v"(dst), "v"(pd) : "memory");
    }
    if (layer && s < 511)  // shadow: stage z0(s+1) for next step's Wk part
      stage_tile<1>(z0f + ((size_t)(s + 1) * 8 + bt) * 8192, azs, tid);
  }
}

// ---------------- y = z1 @ V^T + bco : z1 encoded in zfrag layout ----------------
__global__ __launch_bounds__(64) void out_gemm(const _Float16* __restrict__ z1,
                                               const _Float16* __restrict__ V16,
                                               const float* __restrict__ bco,
                                               float* __restrict__ out) {
  __shared__ __align__(16) _Float16 zt[16][520];
  __shared__ __align__(16) _Float16 vt[16][520];
  const int tid = threadIdx.x;
  const int m = tid & 15, q = tid >> 4;
  const size_t r0 = (size_t)blockIdx.x * 16;  // r = t*128 + b
  for (int idx = tid; idx < 1024; idx += 64) {
    int row = idx >> 6, ch = idx & 63;
    int r = (int)(r0 + row), t = r >> 7, b = r & 127;
    size_t off = (size_t)(t * 8 + (b >> 4)) * 8192 + (size_t)ch * 128 + (b & 15) * 8;
    *(half8*)&zt[row][ch * 8] = *(const half8*)&z1[off];
    *(half8*)&vt[row][ch * 8] = *(const half8*)&V16[(size_t)row * 512 + ch * 8];
  }
  __syncthreads();
  floatx4 acc = {0.f, 0.f, 0.f, 0.f};
#pragma unroll
  for (int kk = 0; kk < 16; ++kk) {
    half8 a = *(const half8*)&zt[m][kk * 32 + q * 8];
    half8 b = *(const half8*)&vt[m][kk * 32 + q * 8];
    acc = __builtin_amdgcn_mfma_f32_16x16x32_f16(a, b, acc, 0, 0, 0);
  }
  if (m < 9) {
#pragma unroll
    for (int rr = 0; rr < 4; ++rr) {
      size_t r = r0 + q * 4 + rr;
      size_t t = r >> 7, b = r & 127;
      out[(b * 512 + t) * 9 + m] = acc[rr] + bco[m];
    }
  }
}

extern "C" void kernel_launch(void* const* d_in, const int* in_sizes, int n_in,
                              void* d_out, int out_size, void* d_ws, size_t ws_size,
                              hipStream_t stream) {
  const float* emb = (const float*)d_in[0];  // [128][512][256]
  const float* Ww  = (const float*)d_in[1];  // [512][256]
  const float* Wb  = (const float*)d_in[2];  // [512]
  const float* Ukw = (const float*)d_in[3];  // [2][512][512] (only [0] used)
  const float* Ukb = (const float*)d_in[4];  // [2][512]      (only [0] used)
  const float* Wkw = (const float*)d_in[5];  // [1][512][512]
  const float* Wkb = (const float*)d_in[6];  // [1][512]
  const float* Vw  = (const float*)d_in[7];  // [9][512]
  const float* Vb  = (const float*)d_in[8];  // [9]
  float* out = (float*)d_out;                // [128][512][9] f32

  char* ws = (char*)d_ws;
  _Float16* xp   = (_Float16*)(ws + 0);          // [T][B][H] f16 t-major, 64 MB
  _Float16* z0f  = (_Float16*)(ws + 67108864);   // zfrag (encoded), 64 MB
  _Float16* z1f  = (_Float16*)(ws + 134217728);  // zfrag (encoded), 64 MB
  _Float16* V16  = (_Float16*)(ws + 201326592);  // 16 KB
  float* bxp     = (float*)(ws + 201342976);
  float* bc      = (float*)(ws + 201345024);
  float* sums    = (float*)(ws + 201347072);     // SU[512], SW[512], bco[16]

  hipLaunchKernelGGL(prep_small, dim3(32), dim3(256), 0, stream,
                     Vw, Vb, Wb, Ukb, Wkb, Ukw, Wkw, V16, bxp, bc, sums);
  hipLaunchKernelGGL(gemm_xp, dim3(512, 4), dim3(256), 0, stream, emb, Ww, xp, bxp);
  hipLaunchKernelGGL(rnn_fused2, dim3(64), dim3(256), 0, stream,
                     Ukw, Wkw, xp, z0f, z1f, bc, sums);
  hipLaunchKernelGGL(out_gemm, dim3(4096), dim3(64), 0, stream, z1f, V16, sums + 1024, out);
}